// Round 3
// baseline (385.955 us; speedup 1.0000x reference)
//
#include <hip/hip_runtime.h>
#include <math.h>

#define N_NODES 65536
#define N_EDGES 655360
#define N_GRAPHS 512
#define NPERG 128
#define KTOP 32
#define NOUT 27
#define OUT0_SIZE (N_GRAPHS * NOUT)   // 13824

typedef unsigned int uint32;
typedef unsigned short ushort16;      // scalar ushort (legacy name)
typedef __attribute__((ext_vector_type(8))) short bf16x8;
typedef __attribute__((ext_vector_type(4))) float f32x4;

__device__ __forceinline__ float blo(uint32 u) { return __uint_as_float(u << 16); }
__device__ __forceinline__ float bhi(uint32 u) { return __uint_as_float(u & 0xffff0000u); }
__device__ __forceinline__ ushort16 f2b(float f) {
    uint32 u = __float_as_uint(f);
    u += 0x7fffu + ((u >> 16) & 1u);   // round-to-nearest-even
    return (ushort16)(u >> 16);
}
__device__ __forceinline__ uint32 pk(float a, float b) {
    return (uint32)f2b(a) | ((uint32)f2b(b) << 16);
}

// ---------------- CSR build ----------------

__global__ void count_kernel(const int* __restrict__ col, int* __restrict__ cnt) {
    int e = blockIdx.x * 256 + threadIdx.x;
    if (e < N_EDGES) atomicAdd(&cnt[col[e]], 1);
}

__global__ void dinv_kernel(const int* __restrict__ cnt, float* __restrict__ dinv) {
    int i = blockIdx.x * 256 + threadIdx.x;
    if (i < N_NODES) dinv[i] = rsqrtf((float)cnt[i] + 1.0f);
}

__global__ void scan1_kernel(const int* __restrict__ cnt, int* __restrict__ ptr, int* __restrict__ bsum) {
    __shared__ int tmp[256];
    int t = threadIdx.x, i = blockIdx.x * 256 + t;
    int v = cnt[i];
    tmp[t] = v; __syncthreads();
    for (int o = 1; o < 256; o <<= 1) {
        int u = (t >= o) ? tmp[t - o] : 0;
        __syncthreads();
        tmp[t] += u;
        __syncthreads();
    }
    ptr[i] = tmp[t] - v;
    if (t == 255) bsum[blockIdx.x] = tmp[t];
}

__global__ void scan2_kernel(int* __restrict__ bsum) {
    __shared__ int tmp[256];
    int t = threadIdx.x;
    int v = bsum[t];
    tmp[t] = v; __syncthreads();
    for (int o = 1; o < 256; o <<= 1) {
        int u = (t >= o) ? tmp[t - o] : 0;
        __syncthreads();
        tmp[t] += u;
        __syncthreads();
    }
    bsum[t] = tmp[t] - v;
}

__global__ void scan3_kernel(int* __restrict__ ptr, const int* __restrict__ bsum) {
    int i = blockIdx.x * 256 + threadIdx.x;
    ptr[i] += bsum[blockIdx.x];
    if (i == 0) ptr[N_NODES] = N_EDGES;
}

// packed edge: (src << 16) | bf16(coef)
__global__ void fill_kernel(const int* __restrict__ row, const int* __restrict__ col,
                            const int* __restrict__ ptr, int* __restrict__ cur,
                            const float* __restrict__ dinv,
                            uint32* __restrict__ ep) {
    int e = blockIdx.x * 256 + threadIdx.x;
    if (e >= N_EDGES) return;
    int r = row[e], d = col[e];
    int p = ptr[d] + atomicAdd(&cur[d], 1);
    ep[p] = ((uint32)r << 16) | (uint32)f2b(dinv[r] * dinv[d]);
}

// ---------------- fp32 -> bf16 convert (layer-1 GEMM input) ----------------

__global__ void cvt_kernel(const float2* __restrict__ x, uint32* __restrict__ xb) {
    int i = blockIdx.x * 256 + threadIdx.x;
    float2 v = x[i];
    xb[i] = pk(v.x, v.y);
}

// ---------------- MFMA GEMM: Y[N][FO](bf16) = Xb[N][FI](bf16) @ W[FI][FO](f32) ----------------
// 64-row blocks, 4 waves. A tile + transposed-W tile in LDS (+1-cell pad -> 2-way free).
// mfma_f32_16x16x32_bf16: A[m=lane&15][k=quad*8+j], B[k=quad*8+j][n=lane&15],
// D: col=lane&15, row=quad*4+reg.

template<int FI, int FO>
__global__ __launch_bounds__(256) void mfma_gemm(const uint4* __restrict__ Xb,
                                                 const float* __restrict__ W,
                                                 uint4* __restrict__ Y) {
    constexpr int KC = FI / 8;        // 16B chunks per row
    constexpr int SA = KC + 1;        // padded stride in cells
    constexpr int NTILE = FO / 16;
    constexpr int CW = (NTILE >= 4) ? 4 : NTILE;   // col-split ways
    constexpr int NTW = NTILE / CW;   // col tiles per wave
    constexpr int RW = 4 / CW;        // row-split ways
    constexpr int RS = 4 / RW;        // 16-row strips per wave (4 strips total)
    constexpr int KSTEPS = FI / 32;

    __shared__ uint4 As[64 * SA];
    __shared__ uint4 Bs[FO * SA];

    int t = threadIdx.x;
    size_t rowbase = (size_t)blockIdx.x * 64;

    // stage A (row-major bf16, padded)
    for (int q = t; q < 64 * KC; q += 256) {
        int r = q / KC, c = q % KC;
        As[r * SA + c] = Xb[(rowbase + r) * KC + c];
    }
    // stage B^T: Bs[n][kchunk] bf16 (transpose + cvt of W)
    for (int q = t; q < FO * KC; q += 256) {
        int c = q / FO, n = q % FO;
        const float* wp = W + (size_t)(c * 8) * FO + n;
        uint4 v;
        v.x = pk(wp[0],        wp[(size_t)FO]);
        v.y = pk(wp[2*(size_t)FO], wp[3*(size_t)FO]);
        v.z = pk(wp[4*(size_t)FO], wp[5*(size_t)FO]);
        v.w = pk(wp[6*(size_t)FO], wp[7*(size_t)FO]);
        Bs[n * SA + c] = v;
    }
    __syncthreads();

    int w = t >> 6, L = t & 63;
    int quad = L >> 4, m = L & 15;
    int cw = w % CW, rw = w / CW;

    f32x4 acc[RS][NTW];
#pragma unroll
    for (int i = 0; i < RS; i++)
#pragma unroll
        for (int j = 0; j < NTW; j++) acc[i][j] = (f32x4)0.f;

    const bf16x8* Asv = (const bf16x8*)As;
    const bf16x8* Bsv = (const bf16x8*)Bs;

#pragma unroll
    for (int ks = 0; ks < KSTEPS; ks++) {
        int kc = ks * 4 + quad;
        bf16x8 bfr[NTW];
#pragma unroll
        for (int j = 0; j < NTW; j++) {
            int n = (cw * NTW + j) * 16 + m;
            bfr[j] = Bsv[n * SA + kc];
        }
#pragma unroll
        for (int i = 0; i < RS; i++) {
            int r = (rw * RS + i) * 16 + m;
            bf16x8 afr = Asv[r * SA + kc];
#pragma unroll
            for (int j = 0; j < NTW; j++)
                acc[i][j] = __builtin_amdgcn_mfma_f32_16x16x32_bf16(afr, bfr[j], acc[i][j], 0, 0, 0);
        }
    }
    __syncthreads();

    // epilogue: D -> LDS [64][FO] bf16 (reuse As region), then coalesced global stores
    ushort16* outs = (ushort16*)As;
#pragma unroll
    for (int i = 0; i < RS; i++) {
        int rb = (rw * RS + i) * 16 + quad * 4;
#pragma unroll
        for (int j = 0; j < NTW; j++) {
            int cc = (cw * NTW + j) * 16 + m;
#pragma unroll
            for (int g = 0; g < 4; g++)
                outs[(rb + g) * FO + cc] = f2b(acc[i][j][g]);
        }
    }
    __syncthreads();
    constexpr int OC = FO / 8;
    for (int q = t; q < 64 * OC; q += 256) {
        Y[rowbase * OC + q] = ((const uint4*)As)[q];
    }
}

// ---------------- Aggregation + self-loop + bias + tanh ----------------
// xw bf16 [N][F]; packed edges; writes h fp32 slice + hb bf16 (next GEMM input).

template<int F>
__global__ __launch_bounds__(256) void agg_kernel(const ushort16* __restrict__ xw,
                                                  const int* __restrict__ ptr,
                                                  const uint32* __restrict__ ep,
                                                  const float* __restrict__ dinv,
                                                  const float* __restrict__ bias,
                                                  float* __restrict__ h, int coloff,
                                                  uint32* __restrict__ hb) {
    constexpr int L = F / 2;               // lanes per node
    int gid = blockIdx.x * 256 + threadIdx.x;
    int n = gid / L;
    int c2 = gid % L;
    int p0 = ptr[n], p1 = ptr[n + 1];
    float s0 = 0.f, s1 = 0.f, t0 = 0.f, t1 = 0.f;
    float u0 = 0.f, u1 = 0.f, v0 = 0.f, v1 = 0.f;
    int p = p0;
    for (; p + 3 < p1; p += 4) {
        uint32 eA = __builtin_nontemporal_load(ep + p);
        uint32 eB = __builtin_nontemporal_load(ep + p + 1);
        uint32 eC = __builtin_nontemporal_load(ep + p + 2);
        uint32 eD = __builtin_nontemporal_load(ep + p + 3);
        uint32 a = *(const uint32*)(xw + (size_t)(eA >> 16) * F + 2 * c2);
        uint32 b = *(const uint32*)(xw + (size_t)(eB >> 16) * F + 2 * c2);
        uint32 c = *(const uint32*)(xw + (size_t)(eC >> 16) * F + 2 * c2);
        uint32 d = *(const uint32*)(xw + (size_t)(eD >> 16) * F + 2 * c2);
        float cA = __uint_as_float(eA << 16), cB = __uint_as_float(eB << 16);
        float cC = __uint_as_float(eC << 16), cD = __uint_as_float(eD << 16);
        s0 += cA * blo(a); s1 += cA * bhi(a);
        t0 += cB * blo(b); t1 += cB * bhi(b);
        u0 += cC * blo(c); u1 += cC * bhi(c);
        v0 += cD * blo(d); v1 += cD * bhi(d);
    }
    for (; p < p1; ++p) {
        uint32 eA = __builtin_nontemporal_load(ep + p);
        uint32 a = *(const uint32*)(xw + (size_t)(eA >> 16) * F + 2 * c2);
        float cA = __uint_as_float(eA << 16);
        s0 += cA * blo(a); s1 += cA * bhi(a);
    }
    s0 += t0 + u0 + v0;
    s1 += t1 + u1 + v1;
    float di = dinv[n];
    uint32 a = *(const uint32*)(xw + (size_t)n * F + 2 * c2);
    float r0 = s0 + di * di * blo(a) + bias[2 * c2];
    float r1 = s1 + di * di * bhi(a) + bias[2 * c2 + 1];
    float2 res;
    res.x = tanhf(r0);
    res.y = tanhf(r1);
    double dres;
    __builtin_memcpy(&dres, &res, 8);
    __builtin_nontemporal_store(dres, (double*)(h + (size_t)n * 256 + coloff + 2 * c2));
    if (hb) __builtin_nontemporal_store(pk(res.x, res.y), hb + (size_t)n * L + c2);
}

// ---------------- Sort-pool + conv5 + maxpool + conv6 + dense (one block per graph) ----------------

__global__ __launch_bounds__(256) void final_kernel(const float* __restrict__ h,
                                                    const float* __restrict__ w5, const float* __restrict__ b5,
                                                    const float* __restrict__ w6, const float* __restrict__ b6,
                                                    const float* __restrict__ dw, const float* __restrict__ db,
                                                    float* __restrict__ out) {
    __shared__ float skey[128];
    __shared__ int   sidx[128];
    __shared__ float ph[32][257];
    __shared__ float w5s[16][256];
    __shared__ float z5[16][33];
    __shared__ float ms[16][17];
    __shared__ float z6[384];
    int g = blockIdx.x, t = threadIdx.x;

    if (t < 128) { skey[t] = h[(size_t)(g * NPERG + t) * 256 + 255]; sidx[t] = t; }
    for (int q = t; q < 16 * 256; q += 256) w5s[q >> 8][q & 255] = w5[q];
    __syncthreads();

    for (int size = 2; size <= 128; size <<= 1) {
        for (int stride = size >> 1; stride > 0; stride >>= 1) {
            if (t < 64) {
                int i = ((t & ~(stride - 1)) << 1) | (t & (stride - 1));
                int j = i | stride;
                float ki = skey[i], kj = skey[j];
                int ii = sidx[i], ij = sidx[j];
                bool desc = ((i & size) == 0);
                bool ibef = (ki > kj) || (ki == kj && ii < ij);
                if (desc != ibef) { skey[i] = kj; skey[j] = ki; sidx[i] = ij; sidx[j] = ii; }
            }
            __syncthreads();
        }
    }

    if (t < KTOP) out[OUT0_SIZE + g * KTOP + t] = (float)(g * NPERG + sidx[t]);

    for (int r = 0; r < KTOP; r++) {
        int node = g * NPERG + sidx[r];
        ph[r][t] = h[(size_t)node * 256 + t];
    }
    __syncthreads();

    {
        int o = t >> 5, l = t & 31;
        float a0 = 0.f, a1 = 0.f;
#pragma unroll 4
        for (int j = 0; j < 256; j++) {
            float pv = ph[l][j];
            a0 += pv * w5s[o][j];
            a1 += pv * w5s[o + 8][j];
        }
        z5[o][l]     = fmaxf(a0 + b5[o], 0.f);
        z5[o + 8][l] = fmaxf(a1 + b5[o + 8], 0.f);
    }
    __syncthreads();

    {
        int o = t >> 4, p = t & 15;
        ms[o][p] = fmaxf(z5[o][2 * p], z5[o][2 * p + 1]);
    }
    __syncthreads();

    for (int q = t; q < 384; q += 256) {
        int o2 = q / 12, tt = q % 12;
        float a = b6[o2];
        for (int o = 0; o < 16; o++) {
#pragma unroll
            for (int k = 0; k < 5; k++)
                a += w6[(o2 * 16 + o) * 5 + k] * ms[o][tt + k];
        }
        z6[q] = fmaxf(a, 0.f);
    }
    __syncthreads();

    if (t < NOUT) {
        float a = db[t];
        for (int i = 0; i < 384; i++) a += z6[i] * dw[i * NOUT + t];
        out[g * NOUT + t] = a;
    }
}

// ---------------- launch ----------------

extern "C" void kernel_launch(void* const* d_in, const int* in_sizes, int n_in,
                              void* d_out, int out_size, void* d_ws, size_t ws_size,
                              hipStream_t stream) {
    const float* x    = (const float*)d_in[0];
    const int*   edge = (const int*)d_in[1];
    const int*   row  = edge;
    const int*   col  = edge + N_EDGES;
    const float* W1 = (const float*)d_in[3];  const float* b1 = (const float*)d_in[4];
    const float* W2 = (const float*)d_in[5];  const float* b2 = (const float*)d_in[6];
    const float* W3 = (const float*)d_in[7];  const float* b3 = (const float*)d_in[8];
    const float* W4 = (const float*)d_in[9];  const float* b4 = (const float*)d_in[10];
    const float* w5 = (const float*)d_in[11]; const float* b5 = (const float*)d_in[12];
    const float* w6 = (const float*)d_in[13]; const float* b6 = (const float*)d_in[14];
    const float* dw = (const float*)d_in[15]; const float* db = (const float*)d_in[16];
    float* out = (float*)d_out;

    char* wsb = (char*)d_ws;
    size_t off = 0;
    auto alloc = [&](size_t bytes) -> void* {
        void* p = wsb + off;
        off = (off + bytes + 255) & ~(size_t)255;
        return p;
    };
    float*    dinv = (float*)alloc((size_t)N_NODES * 4);
    int*      cnt  = (int*)  alloc((size_t)N_NODES * 4);
    int*      ptr  = (int*)  alloc((size_t)(N_NODES + 1) * 4);
    int*      bsum = (int*)  alloc(256 * 4);
    uint32*   ep   = (uint32*)alloc((size_t)N_EDGES * 4);
    ushort16* xw   = (ushort16*)alloc((size_t)N_NODES * 128 * 2);
    uint32*   hb   = (uint32*)alloc((size_t)N_NODES * 128 * 2);
    float*    h    = (float*)alloc((size_t)N_NODES * 256 * 4);
    (void)ws_size; (void)in_sizes; (void)n_in; (void)out_size;

    hipMemsetAsync(cnt, 0, (size_t)N_NODES * 4, stream);
    count_kernel<<<N_EDGES / 256, 256, 0, stream>>>(col, cnt);
    dinv_kernel<<<N_NODES / 256, 256, 0, stream>>>(cnt, dinv);
    scan1_kernel<<<256, 256, 0, stream>>>(cnt, ptr, bsum);
    scan2_kernel<<<1, 256, 0, stream>>>(bsum);
    scan3_kernel<<<256, 256, 0, stream>>>(ptr, bsum);
    hipMemsetAsync(cnt, 0, (size_t)N_NODES * 4, stream);
    fill_kernel<<<N_EDGES / 256, 256, 0, stream>>>(row, col, ptr, cnt, dinv, ep);

    cvt_kernel<<<(N_NODES * 128 / 2) / 256, 256, 0, stream>>>((const float2*)x, hb);

    mfma_gemm<128, 128><<<N_NODES / 64, 256, 0, stream>>>((const uint4*)hb, W1, (uint4*)xw);
    agg_kernel<128><<<(N_NODES * 64) / 256, 256, 0, stream>>>(xw, ptr, ep, dinv, b1, h, 0, hb);

    mfma_gemm<128, 64><<<N_NODES / 64, 256, 0, stream>>>((const uint4*)hb, W2, (uint4*)xw);
    agg_kernel<64><<<(N_NODES * 32) / 256, 256, 0, stream>>>(xw, ptr, ep, dinv, b2, h, 128, hb);

    mfma_gemm<64, 32><<<N_NODES / 64, 256, 0, stream>>>((const uint4*)hb, W3, (uint4*)xw);
    agg_kernel<32><<<(N_NODES * 16) / 256, 256, 0, stream>>>(xw, ptr, ep, dinv, b3, h, 192, hb);

    mfma_gemm<32, 32><<<N_NODES / 64, 256, 0, stream>>>((const uint4*)hb, W4, (uint4*)xw);
    agg_kernel<32><<<(N_NODES * 16) / 256, 256, 0, stream>>>(xw, ptr, ep, dinv, b4, h, 224, (uint32*)nullptr);

    final_kernel<<<N_GRAPHS, 256, 0, stream>>>(h, w5, b5, w6, b6, dw, db, out);
}

// Round 4
// 304.101 us; speedup vs baseline: 1.2692x; 1.2692x over previous
//
#include <hip/hip_runtime.h>
#include <math.h>

#define N_NODES 65536
#define N_EDGES 655360
#define N_GRAPHS 512
#define NPERG 128
#define KTOP 32
#define NOUT 27
#define OUT0_SIZE (N_GRAPHS * NOUT)   // 13824
#define EP_CAP (N_EDGES + 8 * N_NODES)

typedef unsigned int uint32;
typedef unsigned short ushort16;      // scalar ushort

typedef __attribute__((ext_vector_type(8))) short bf16x8;
typedef __attribute__((ext_vector_type(4))) float f32x4;

__device__ __forceinline__ float blo(uint32 u) { return __uint_as_float(u << 16); }
__device__ __forceinline__ float bhi(uint32 u) { return __uint_as_float(u & 0xffff0000u); }
__device__ __forceinline__ float b2f(ushort16 u) { return __uint_as_float((uint32)u << 16); }
__device__ __forceinline__ ushort16 f2b(float f) {
    uint32 u = __float_as_uint(f);
    u += 0x7fffu + ((u >> 16) & 1u);   // round-to-nearest-even
    return (ushort16)(u >> 16);
}
__device__ __forceinline__ uint32 pk(float a, float b) {
    return (uint32)f2b(a) | ((uint32)f2b(b) << 16);
}

// ---------------- CSR build (degree lists padded to multiples of 8) ----------------

__global__ void count_kernel(const int* __restrict__ col, int* __restrict__ cnt) {
    int e = blockIdx.x * 256 + threadIdx.x;
    if (e < N_EDGES) atomicAdd(&cnt[col[e]], 1);
}

__global__ void dinv_kernel(const int* __restrict__ cnt, float* __restrict__ dinv) {
    int i = blockIdx.x * 256 + threadIdx.x;
    if (i < N_NODES) dinv[i] = rsqrtf((float)cnt[i] + 1.0f);
}

__global__ void scan1_kernel(const int* __restrict__ cnt, int* __restrict__ ptr, int* __restrict__ bsum) {
    __shared__ int tmp[256];
    int t = threadIdx.x, i = blockIdx.x * 256 + t;
    int v = (cnt[i] + 7) & ~7;        // padded degree
    tmp[t] = v; __syncthreads();
    for (int o = 1; o < 256; o <<= 1) {
        int u = (t >= o) ? tmp[t - o] : 0;
        __syncthreads();
        tmp[t] += u;
        __syncthreads();
    }
    ptr[i] = tmp[t] - v;
    if (t == 255) bsum[blockIdx.x] = tmp[t];
}

__global__ void scan2_kernel(int* __restrict__ bsum, int* __restrict__ ptr) {
    __shared__ int tmp[256];
    int t = threadIdx.x;
    int v = bsum[t];
    tmp[t] = v; __syncthreads();
    for (int o = 1; o < 256; o <<= 1) {
        int u = (t >= o) ? tmp[t - o] : 0;
        __syncthreads();
        tmp[t] += u;
        __syncthreads();
    }
    bsum[t] = tmp[t] - v;
    if (t == 255) ptr[N_NODES] = tmp[t];   // total padded edges
}

__global__ void scan3_kernel(int* __restrict__ ptr, const int* __restrict__ bsum) {
    int i = blockIdx.x * 256 + threadIdx.x;
    ptr[i] += bsum[blockIdx.x];
}

// packed edge: (src << 16) | bf16(coef); padding slots stay 0 (src 0, coef +0.0)
__global__ void fill_kernel(const int* __restrict__ row, const int* __restrict__ col,
                            const int* __restrict__ ptr, int* __restrict__ cur,
                            const float* __restrict__ dinv,
                            uint32* __restrict__ ep) {
    int e = blockIdx.x * 256 + threadIdx.x;
    if (e >= N_EDGES) return;
    int r = row[e], d = col[e];
    int p = ptr[d] + atomicAdd(&cur[d], 1);
    ep[p] = ((uint32)r << 16) | (uint32)f2b(dinv[r] * dinv[d]);
}

// ---------------- MFMA GEMM: Y[N][FO](bf16) = X[N][FI] @ W[FI][FO](f32) ----------------
// 64-row blocks, 4 waves. A tile + transposed-W tile in LDS (+1-cell pad).
// mfma_f32_16x16x32_bf16: A[m=lane&15][k=quad*8+j], B[k][n=lane&15],
// D: col=lane&15, row=quad*4+reg.

template<int FI, int FO, bool F32IN>
__global__ __launch_bounds__(256) void mfma_gemm(const void* __restrict__ Xin, int pitch,
                                                 const float* __restrict__ W,
                                                 uint4* __restrict__ Y) {
    constexpr int KC = FI / 8;        // 16B cells per row
    constexpr int SA = KC + 1;
    constexpr int NTILE = FO / 16;
    constexpr int CW = (NTILE >= 4) ? 4 : NTILE;
    constexpr int NTW = NTILE / CW;
    constexpr int RW = 4 / CW;
    constexpr int RS = 4 / RW;
    constexpr int KSTEPS = FI / 32;

    __shared__ uint4 As[64 * SA];
    __shared__ uint4 Bs[FO * SA];

    int t = threadIdx.x;
    size_t rowbase = (size_t)blockIdx.x * 64;

    if constexpr (F32IN) {
        const float* X = (const float*)Xin;
        for (int q = t; q < 64 * KC; q += 256) {
            int r = q / KC, c = q % KC;
            const float* xp = X + (size_t)(rowbase + r) * pitch + c * 8;
            float4 v0 = *(const float4*)xp;
            float4 v1 = *(const float4*)(xp + 4);
            uint4 u;
            u.x = pk(v0.x, v0.y); u.y = pk(v0.z, v0.w);
            u.z = pk(v1.x, v1.y); u.w = pk(v1.z, v1.w);
            As[r * SA + c] = u;
        }
    } else {
        const uint4* Xb = (const uint4*)Xin;
        int pc = pitch / 8;
        for (int q = t; q < 64 * KC; q += 256) {
            int r = q / KC, c = q % KC;
            As[r * SA + c] = Xb[(size_t)(rowbase + r) * pc + c];
        }
    }
    // stage B^T: Bs[n][kchunk] bf16 (transpose + cvt of W)
    for (int q = t; q < FO * KC; q += 256) {
        int c = q / FO, n = q % FO;
        const float* wp = W + (size_t)(c * 8) * FO + n;
        uint4 v;
        v.x = pk(wp[0],            wp[(size_t)FO]);
        v.y = pk(wp[2*(size_t)FO], wp[3*(size_t)FO]);
        v.z = pk(wp[4*(size_t)FO], wp[5*(size_t)FO]);
        v.w = pk(wp[6*(size_t)FO], wp[7*(size_t)FO]);
        Bs[n * SA + c] = v;
    }
    __syncthreads();

    int w = t >> 6, L = t & 63;
    int quad = L >> 4, m = L & 15;
    int cw = w % CW, rw = w / CW;

    f32x4 acc[RS][NTW];
#pragma unroll
    for (int i = 0; i < RS; i++)
#pragma unroll
        for (int j = 0; j < NTW; j++) acc[i][j] = (f32x4)0.f;

    const bf16x8* Asv = (const bf16x8*)As;
    const bf16x8* Bsv = (const bf16x8*)Bs;

#pragma unroll
    for (int ks = 0; ks < KSTEPS; ks++) {
        int kc = ks * 4 + quad;
        bf16x8 bfr[NTW];
#pragma unroll
        for (int j = 0; j < NTW; j++) {
            int n = (cw * NTW + j) * 16 + m;
            bfr[j] = Bsv[n * SA + kc];
        }
#pragma unroll
        for (int i = 0; i < RS; i++) {
            int r = (rw * RS + i) * 16 + m;
            bf16x8 afr = Asv[r * SA + kc];
#pragma unroll
            for (int j = 0; j < NTW; j++)
                acc[i][j] = __builtin_amdgcn_mfma_f32_16x16x32_bf16(afr, bfr[j], acc[i][j], 0, 0, 0);
        }
    }
    __syncthreads();

    // epilogue: D -> LDS [64][FO] bf16 (reuse As), then coalesced 16B stores
    ushort16* outs = (ushort16*)As;
#pragma unroll
    for (int i = 0; i < RS; i++) {
        int rb = (rw * RS + i) * 16 + quad * 4;
#pragma unroll
        for (int j = 0; j < NTW; j++) {
            int cc = (cw * NTW + j) * 16 + m;
#pragma unroll
            for (int g = 0; g < 4; g++)
                outs[(rb + g) * FO + cc] = f2b(acc[i][j][g]);
        }
    }
    __syncthreads();
    constexpr int OC = FO / 8;
    for (int q = t; q < 64 * OC; q += 256) {
        Y[rowbase * OC + q] = ((const uint4*)As)[q];
    }
}

// ---------------- Aggregation + self-loop + bias + tanh -> bf16 hcat slice ----------------
// xw2: [N][F/2] uint32 (bf16 pairs). Edge lists padded to 8 -> tail-free 8-wide gather.

template<int F>
__global__ __launch_bounds__(256) void agg_kernel(const uint32* __restrict__ xw2,
                                                  const int* __restrict__ ptr,
                                                  const uint32* __restrict__ ep,
                                                  const float* __restrict__ dinv,
                                                  const float* __restrict__ bias,
                                                  uint32* __restrict__ hc, int coloff2) {
    constexpr int L = F / 2;
    int gid = blockIdx.x * 256 + threadIdx.x;
    int n = gid / L;
    int c2 = gid % L;
    int p0 = ptr[n], p1 = ptr[n + 1];
    float s0 = 0.f, s1 = 0.f, t0 = 0.f, t1 = 0.f;
    float u0 = 0.f, u1 = 0.f, v0 = 0.f, v1 = 0.f;
    for (int p = p0; p < p1; p += 8) {
        uint4 ea = *(const uint4*)(ep + p);
        uint4 eb = *(const uint4*)(ep + p + 4);
        uint32 g0 = xw2[(size_t)(ea.x >> 16) * L + c2];
        uint32 g1 = xw2[(size_t)(ea.y >> 16) * L + c2];
        uint32 g2 = xw2[(size_t)(ea.z >> 16) * L + c2];
        uint32 g3 = xw2[(size_t)(ea.w >> 16) * L + c2];
        uint32 g4 = xw2[(size_t)(eb.x >> 16) * L + c2];
        uint32 g5 = xw2[(size_t)(eb.y >> 16) * L + c2];
        uint32 g6 = xw2[(size_t)(eb.z >> 16) * L + c2];
        uint32 g7 = xw2[(size_t)(eb.w >> 16) * L + c2];
        float c0 = __uint_as_float(ea.x << 16), c1 = __uint_as_float(ea.y << 16);
        float c2f = __uint_as_float(ea.z << 16), c3 = __uint_as_float(ea.w << 16);
        float c4 = __uint_as_float(eb.x << 16), c5 = __uint_as_float(eb.y << 16);
        float c6 = __uint_as_float(eb.z << 16), c7 = __uint_as_float(eb.w << 16);
        s0 += c0 * blo(g0); s1 += c0 * bhi(g0);
        t0 += c1 * blo(g1); t1 += c1 * bhi(g1);
        u0 += c2f * blo(g2); u1 += c2f * bhi(g2);
        v0 += c3 * blo(g3); v1 += c3 * bhi(g3);
        s0 += c4 * blo(g4); s1 += c4 * bhi(g4);
        t0 += c5 * blo(g5); t1 += c5 * bhi(g5);
        u0 += c6 * blo(g6); u1 += c6 * bhi(g6);
        v0 += c7 * blo(g7); v1 += c7 * bhi(g7);
    }
    s0 += t0 + u0 + v0;
    s1 += t1 + u1 + v1;
    float di = dinv[n];
    uint32 a = xw2[(size_t)n * L + c2];
    float r0 = s0 + di * di * blo(a) + bias[2 * c2];
    float r1 = s1 + di * di * bhi(a) + bias[2 * c2 + 1];
    hc[(size_t)n * 128 + coloff2 + c2] = pk(tanhf(r0), tanhf(r1));
}

// ---------------- Sort-pool + conv5 + maxpool + conv6 + dense (one block per graph) ----------------

__global__ __launch_bounds__(256) void final_kernel(const ushort16* __restrict__ hcat,
                                                    const float* __restrict__ w5, const float* __restrict__ b5,
                                                    const float* __restrict__ w6, const float* __restrict__ b6,
                                                    const float* __restrict__ dw, const float* __restrict__ db,
                                                    float* __restrict__ out) {
    __shared__ float skey[128];
    __shared__ int   sidx[128];
    __shared__ float ph[32][257];
    __shared__ float w5s[16][256];
    __shared__ float z5[16][33];
    __shared__ float ms[16][17];
    __shared__ float z6[384];
    int g = blockIdx.x, t = threadIdx.x;

    if (t < 128) { skey[t] = b2f(hcat[(size_t)(g * NPERG + t) * 256 + 255]); sidx[t] = t; }
    for (int q = t; q < 16 * 256; q += 256) w5s[q >> 8][q & 255] = w5[q];
    __syncthreads();

    // bitonic sort: key desc, index asc on ties (== stable argsort(-key))
    for (int size = 2; size <= 128; size <<= 1) {
        for (int stride = size >> 1; stride > 0; stride >>= 1) {
            if (t < 64) {
                int i = ((t & ~(stride - 1)) << 1) | (t & (stride - 1));
                int j = i | stride;
                float ki = skey[i], kj = skey[j];
                int ii = sidx[i], ij = sidx[j];
                bool desc = ((i & size) == 0);
                bool ibef = (ki > kj) || (ki == kj && ii < ij);
                if (desc != ibef) { skey[i] = kj; skey[j] = ki; sidx[i] = ij; sidx[j] = ii; }
            }
            __syncthreads();
        }
    }

    if (t < KTOP) out[OUT0_SIZE + g * KTOP + t] = (float)(g * NPERG + sidx[t]);

    for (int r = 0; r < KTOP; r++) {
        int node = g * NPERG + sidx[r];
        ph[r][t] = b2f(hcat[(size_t)node * 256 + t]);
    }
    __syncthreads();

    {
        int o = t >> 5, l = t & 31;
        float a0 = 0.f, a1 = 0.f;
#pragma unroll 4
        for (int j = 0; j < 256; j++) {
            float pv = ph[l][j];
            a0 += pv * w5s[o][j];
            a1 += pv * w5s[o + 8][j];
        }
        z5[o][l]     = fmaxf(a0 + b5[o], 0.f);
        z5[o + 8][l] = fmaxf(a1 + b5[o + 8], 0.f);
    }
    __syncthreads();

    {
        int o = t >> 4, p = t & 15;
        ms[o][p] = fmaxf(z5[o][2 * p], z5[o][2 * p + 1]);
    }
    __syncthreads();

    for (int q = t; q < 384; q += 256) {
        int o2 = q / 12, tt = q % 12;
        float a = b6[o2];
        for (int o = 0; o < 16; o++) {
#pragma unroll
            for (int k = 0; k < 5; k++)
                a += w6[(o2 * 16 + o) * 5 + k] * ms[o][tt + k];
        }
        z6[q] = fmaxf(a, 0.f);
    }
    __syncthreads();

    if (t < NOUT) {
        float a = db[t];
        for (int i = 0; i < 384; i++) a += z6[i] * dw[i * NOUT + t];
        out[g * NOUT + t] = a;
    }
}

// ---------------- launch ----------------

extern "C" void kernel_launch(void* const* d_in, const int* in_sizes, int n_in,
                              void* d_out, int out_size, void* d_ws, size_t ws_size,
                              hipStream_t stream) {
    const float* x    = (const float*)d_in[0];
    const int*   edge = (const int*)d_in[1];
    const int*   row  = edge;
    const int*   col  = edge + N_EDGES;
    const float* W1 = (const float*)d_in[3];  const float* b1 = (const float*)d_in[4];
    const float* W2 = (const float*)d_in[5];  const float* b2 = (const float*)d_in[6];
    const float* W3 = (const float*)d_in[7];  const float* b3 = (const float*)d_in[8];
    const float* W4 = (const float*)d_in[9];  const float* b4 = (const float*)d_in[10];
    const float* w5 = (const float*)d_in[11]; const float* b5 = (const float*)d_in[12];
    const float* w6 = (const float*)d_in[13]; const float* b6 = (const float*)d_in[14];
    const float* dw = (const float*)d_in[15]; const float* db = (const float*)d_in[16];
    float* out = (float*)d_out;

    char* wsb = (char*)d_ws;
    size_t off = 0;
    auto alloc = [&](size_t bytes) -> void* {
        void* p = wsb + off;
        off = (off + bytes + 255) & ~(size_t)255;
        return p;
    };
    float*    dinv = (float*)alloc((size_t)N_NODES * 4);
    int*      cnt  = (int*)  alloc((size_t)N_NODES * 4);
    int*      ptr  = (int*)  alloc((size_t)(N_NODES + 1) * 4);
    int*      bsum = (int*)  alloc(256 * 4);
    uint32*   ep   = (uint32*)alloc((size_t)EP_CAP * 4);
    uint32*   xw   = (uint32*)alloc((size_t)N_NODES * 64 * 4);   // [N][128] bf16
    ushort16* hcat = (ushort16*)alloc((size_t)N_NODES * 256 * 2); // [N][256] bf16
    (void)ws_size; (void)in_sizes; (void)n_in; (void)out_size;

    hipMemsetAsync(cnt, 0, (size_t)N_NODES * 4, stream);
    hipMemsetAsync(ep, 0, (size_t)EP_CAP * 4, stream);
    count_kernel<<<N_EDGES / 256, 256, 0, stream>>>(col, cnt);
    dinv_kernel<<<N_NODES / 256, 256, 0, stream>>>(cnt, dinv);
    scan1_kernel<<<256, 256, 0, stream>>>(cnt, ptr, bsum);
    scan2_kernel<<<1, 256, 0, stream>>>(bsum, ptr);
    scan3_kernel<<<256, 256, 0, stream>>>(ptr, bsum);
    hipMemsetAsync(cnt, 0, (size_t)N_NODES * 4, stream);
    fill_kernel<<<N_EDGES / 256, 256, 0, stream>>>(row, col, ptr, cnt, dinv, ep);

    uint32* hc = (uint32*)hcat;

    mfma_gemm<128, 128, true><<<N_NODES / 64, 256, 0, stream>>>(x, 128, W1, (uint4*)xw);
    agg_kernel<128><<<(N_NODES * 64) / 256, 256, 0, stream>>>(xw, ptr, ep, dinv, b1, hc, 0);

    mfma_gemm<128, 64, false><<<N_NODES / 64, 256, 0, stream>>>(hcat, 256, W2, (uint4*)xw);
    agg_kernel<64><<<(N_NODES * 32) / 256, 256, 0, stream>>>(xw, ptr, ep, dinv, b2, hc, 64);

    mfma_gemm<64, 32, false><<<N_NODES / 64, 256, 0, stream>>>(hcat + 128, 256, W3, (uint4*)xw);
    agg_kernel<32><<<(N_NODES * 16) / 256, 256, 0, stream>>>(xw, ptr, ep, dinv, b3, hc, 96);

    mfma_gemm<32, 32, false><<<N_NODES / 64, 256, 0, stream>>>(hcat + 192, 256, W4, (uint4*)xw);
    agg_kernel<32><<<(N_NODES * 16) / 256, 256, 0, stream>>>(xw, ptr, ep, dinv, b4, hc, 112);

    final_kernel<<<N_GRAPHS, 256, 0, stream>>>(hcat, w5, b5, w6, b6, dw, db, out);
}